// Round 1
// baseline (432.288 us; speedup 1.0000x reference)
//
#include <hip/hip_runtime.h>
#include <hip/hip_bf16.h>
#include <hip/hip_fp16.h>

typedef _Float16 f16;
typedef _Float16 half8 __attribute__((ext_vector_type(8)));
typedef float f32x4 __attribute__((ext_vector_type(4)));

#define BM 128
#define BN 128
#define BK 32

__device__ __forceinline__ float gelu_f(float x) {
  return 0.5f * x * (1.0f + erff(x * 0.70710678118654752f));
}

__device__ __forceinline__ void gll16(const void* g, void* l) {
  __builtin_amdgcn_global_load_lds((const __attribute__((address_space(1))) void*)g,
                                   (__attribute__((address_space(3))) void*)l,
                                   16, 0, 0);
}

// D[M][N] = act( P[M][K] * Q[N][K]^T + bias ), both P,Q fp16 K-inner.
// BIAS: 0 none, 1 by row (m), 2 by col (n). KSPLIT: write f32 partial at Dv + z*M*N.
template<int BIAS, bool GELU_ACT, bool OUT_F16, bool KSPLIT>
__global__ __launch_bounds__(256)
void gemm_tn(const f16* __restrict__ P, size_t sP, int ldP,
             const f16* __restrict__ Q, size_t sQ, int ldQ,
             void* __restrict__ Dv, size_t sD, int ldD,
             const float* __restrict__ bias,
             int M, int N, int K, int nks)
{
  __shared__ __align__(16) f16 ldsA[BM * BK];
  __shared__ __align__(16) f16 ldsB[BM * BK];

  const int t = threadIdx.x;
  const int l = t & 63;
  const int wid = t >> 6;
  const int wr = wid >> 1;
  const int wc = wid & 1;

  const int z = blockIdx.z;
  const int b = z / nks;
  const int s = z - b * nks;
  const int kLen = K / nks;
  const int k0 = s * kLen;

  const int mBase = blockIdx.y * BM;
  const int nBase = blockIdx.x * BN;

  const f16* Pb = P + (size_t)b * sP;
  const f16* Qb = Q + (size_t)b * sQ;

  f32x4 acc[4][4];
#pragma unroll
  for (int i = 0; i < 4; ++i)
#pragma unroll
    for (int j = 0; j < 4; ++j)
      acc[i][j] = (f32x4){0.f, 0.f, 0.f, 0.f};

  const int nk = kLen / BK;
  for (int kt = 0; kt < nk; ++kt) {
    const int kk = k0 + kt * BK;
    // stage A and B tiles [128 rows][32 k] fp16, 2 x 4KB calls each.
    // XOR swizzle: physical 16B-chunk pc stores logical chunk pc ^ ((row>>1)&3)
    // (involution; applied on the GLOBAL source here, and on the ds_read below).
#pragma unroll
    for (int c = 0; c < 2; ++c) {
      const int off = c * 4096 + wid * 1024 + l * 16;   // linear LDS byte offset
      const int row = off >> 6;
      const int gch = ((off >> 4) & 3) ^ ((row >> 1) & 3);
      gll16(Pb + (size_t)(mBase + row) * ldP + kk + gch * 8,
            (char*)ldsA + c * 4096 + wid * 1024);
      gll16(Qb + (size_t)(nBase + row) * ldQ + kk + gch * 8,
            (char*)ldsB + c * 4096 + wid * 1024);
    }
    asm volatile("s_waitcnt vmcnt(0)" ::: "memory");
    __syncthreads();

    half8 af[4], bf[4];
#pragma unroll
    for (int mi = 0; mi < 4; ++mi) {
      const int row = wr * 64 + mi * 16 + (l & 15);
      const int phys = row * 64 + ((((l >> 4) ^ (row >> 1)) & 3) << 4);
      af[mi] = *(const half8*)((const char*)ldsA + phys);
    }
#pragma unroll
    for (int ni = 0; ni < 4; ++ni) {
      const int row = wc * 64 + ni * 16 + (l & 15);
      const int phys = row * 64 + ((((l >> 4) ^ (row >> 1)) & 3) << 4);
      bf[ni] = *(const half8*)((const char*)ldsB + phys);
    }
#pragma unroll
    for (int mi = 0; mi < 4; ++mi)
#pragma unroll
      for (int ni = 0; ni < 4; ++ni)
        acc[mi][ni] = __builtin_amdgcn_mfma_f32_16x16x32_f16(af[mi], bf[ni], acc[mi][ni], 0, 0, 0);
    __syncthreads();
  }

  float* Dsplit = nullptr; f16* D16 = nullptr; float* D32 = nullptr;
  if (KSPLIT)      Dsplit = (float*)Dv + (size_t)z * (size_t)(M * N);
  else if (OUT_F16) D16   = (f16*)Dv + (size_t)b * sD;
  else              D32   = (float*)Dv + (size_t)b * sD;

#pragma unroll
  for (int mi = 0; mi < 4; ++mi) {
    const int rb = mBase + wr * 64 + mi * 16 + ((l >> 4) << 2);
#pragma unroll
    for (int ni = 0; ni < 4; ++ni) {
      const int col = nBase + wc * 64 + ni * 16 + (l & 15);
#pragma unroll
      for (int j = 0; j < 4; ++j) {
        float v = acc[mi][ni][j];
        const int rr = rb + j;
        if (BIAS == 1) v += bias[rr];
        if (BIAS == 2) v += bias[col];
        if (GELU_ACT) v = gelu_f(v);
        if (KSPLIT)       Dsplit[(size_t)rr * ldD + col] = v;
        else if (OUT_F16) D16[(size_t)rr * ldD + col] = (f16)v;
        else              D32[(size_t)rr * ldD + col] = v;
      }
    }
  }
}

// in: [b][256][4096] f32 -> out: [b][4096][256] fp16
__global__ __launch_bounds__(256)
void transpose_cvt(const float* __restrict__ in, f16* __restrict__ outp) {
  __shared__ float tile[32][33];
  const int b = blockIdx.z;
  const int c0 = blockIdx.y * 32;
  const int n0 = blockIdx.x * 32;
  const int tx = threadIdx.x & 31;
  const int ty = threadIdx.x >> 5;
  const float* ib = in + (size_t)b * (256 * 4096);
  f16* ob = outp + (size_t)b * (256 * 4096);
#pragma unroll
  for (int i = 0; i < 4; ++i)
    tile[ty + i * 8][tx] = ib[(size_t)(c0 + ty + i * 8) * 4096 + n0 + tx];
  __syncthreads();
#pragma unroll
  for (int i = 0; i < 4; ++i)
    ob[(size_t)(n0 + ty + i * 8) * 256 + c0 + tx] = (f16)tile[tx][ty + i * 8];
}

__global__ void cvt16(const float* __restrict__ in, f16* __restrict__ outp, int n) {
  int i = blockIdx.x * blockDim.x + threadIdx.x;
  if (i < n) outp[i] = (f16)in[i];
}

// qkp: [16*nks][256][256] f32 partials; p: [16][256][256] fp16 softmax rows.
__global__ __launch_bounds__(256)
void softmax_k(const float* __restrict__ qkp, f16* __restrict__ p, int nks) {
  const int t = threadIdx.x;
  const int wid = t >> 6, l = t & 63;
  const int r = blockIdx.x * 4 + wid;   // global row in [0, 16*256)
  const int b = r >> 8, c = r & 255;
  float v[4] = {0.f, 0.f, 0.f, 0.f};
  for (int s = 0; s < nks; ++s) {
    const float* base = qkp + (size_t)(b * nks + s) * 65536 + (size_t)c * 256;
#pragma unroll
    for (int j = 0; j < 4; ++j) v[j] += base[l + 64 * j];
  }
  float m = fmaxf(fmaxf(v[0], v[1]), fmaxf(v[2], v[3]));
#pragma unroll
  for (int off = 32; off; off >>= 1) m = fmaxf(m, __shfl_xor(m, off));
  float e[4], sum = 0.f;
#pragma unroll
  for (int j = 0; j < 4; ++j) { e[j] = expf(v[j] - m); sum += e[j]; }
#pragma unroll
  for (int off = 32; off; off >>= 1) sum += __shfl_xor(sum, off);
  const float inv = 1.0f / sum;
  f16* pb = p + (size_t)r * 256;
#pragma unroll
  for (int j = 0; j < 4; ++j) pb[l + 64 * j] = (f16)(e[j] * inv);
}

extern "C" void kernel_launch(void* const* d_in, const int* in_sizes, int n_in,
                              void* d_out, int out_size, void* d_ws, size_t ws_size,
                              hipStream_t stream) {
  const float* x      = (const float*)d_in[0];
  const float* qin    = (const float*)d_in[1];
  const float* w_kvl  = (const float*)d_in[2];
  const float* b_kvl  = (const float*)d_in[3];
  const float* w_q    = (const float*)d_in[4];
  const float* b_q    = (const float*)d_in[5];
  const float* w_proj = (const float*)d_in[6];
  const float* b_proj = (const float*)d_in[7];
  float* out = (float*)d_out;
  char* ws = (char*)d_ws;

  if (ws_size < 235667456) return;  // need ~225 MB

  f16* xt   = (f16*)(ws + 0);           // [16][4096][256] fp16 (x^T)
  f16* qt   = (f16*)(ws + 33554432);    // [16][4096][256] fp16 (q_input^T)
  f16* wk   = (f16*)(ws + 67108864);    // [768][256]
  f16* wq   = (f16*)(ws + 67502080);    // [256][256]
  f16* wp   = (f16*)(ws + 67633152);    // [256][512]
  f16* kH   = (f16*)(ws + 67895296);    // [16][256][4096]
  f16* qH   = (f16*)(ws + 101449728);   // [16][256][4096]
  f16* vt   = (f16*)(ws + 135004160);   // [16][4096][256] (v^T)
  f16* catT = (f16*)(ws + 168558592);   // [16][4096][512] ([lfeat^T | x2^T])
  float* qkp = (float*)xt;              // reuse: [128][256][256] f32 (xt dead by then)
  f16* pH = qt;                         // reuse: [16][256][256] fp16 (qt dead by then)

  const size_t sAct = 1048576;   // 4096*256 elements per batch
  dim3 blk(256);

  transpose_cvt<<<dim3(128, 8, 16), blk, 0, stream>>>(x, xt);
  transpose_cvt<<<dim3(128, 8, 16), blk, 0, stream>>>(qin, qt);
  cvt16<<<dim3(768), blk, 0, stream>>>(w_kvl, wk, 196608);
  cvt16<<<dim3(256), blk, 0, stream>>>(w_q, wq, 65536);
  cvt16<<<dim3(512), blk, 0, stream>>>(w_proj, wp, 131072);

  // k = gelu(Wkvl[256:512]·x + b): D[d][n] -> kH
  hipLaunchKernelGGL((gemm_tn<1, true, true, false>), dim3(32, 2, 16), blk, 0, stream,
      wk + 65536, (size_t)0, 256, xt, sAct, 256,
      (void*)kH, sAct, 4096, b_kvl + 256, 256, 4096, 256, 1);
  // lfeat^T = gelu(x^T·Wkvl[0:256]^T + b): D[n][c] -> catT[:, 0:256]
  hipLaunchKernelGGL((gemm_tn<2, true, true, false>), dim3(2, 32, 16), blk, 0, stream,
      xt, sAct, 256, wk, (size_t)0, 256,
      (void*)catT, (size_t)2097152, 512, b_kvl, 4096, 256, 256, 1);
  // v^T = gelu(x^T·Wkvl[512:768]^T + b): D[n][d] -> vt
  hipLaunchKernelGGL((gemm_tn<2, true, true, false>), dim3(2, 32, 16), blk, 0, stream,
      xt, sAct, 256, wk + 131072, (size_t)0, 256,
      (void*)vt, sAct, 256, b_kvl + 512, 4096, 256, 256, 1);
  // q = Wq·q_input + b: D[c][n] -> qH
  hipLaunchKernelGGL((gemm_tn<1, false, true, false>), dim3(32, 2, 16), blk, 0, stream,
      wq, (size_t)0, 256, qt, sAct, 256,
      (void*)qH, sAct, 4096, b_q, 256, 4096, 256, 1);
  // qk partials: split-K=8 over n, D f32 [z][256][256]
  hipLaunchKernelGGL((gemm_tn<0, false, false, true>), dim3(2, 2, 128), blk, 0, stream,
      qH, sAct, 4096, kH, sAct, 4096,
      (void*)qkp, (size_t)0, 256, (const float*)nullptr, 256, 256, 4096, 8);
  // softmax over d with split reduction
  softmax_k<<<dim3(1024), blk, 0, stream>>>(qkp, pH, 8);
  // x2^T = v^T·p^T: D[n][c] -> catT[:, 256:512]
  hipLaunchKernelGGL((gemm_tn<0, false, true, false>), dim3(2, 32, 16), blk, 0, stream,
      vt, sAct, 256, pH, (size_t)65536, 256,
      (void*)(catT + 256), (size_t)2097152, 512, (const float*)nullptr, 4096, 256, 256, 1);
  // out = gelu(Wproj·cat + b): D[o][n] f32 -> d_out
  hipLaunchKernelGGL((gemm_tn<1, true, false, false>), dim3(32, 2, 16), blk, 0, stream,
      wp, (size_t)0, 512, catT, (size_t)2097152, 512,
      (void*)out, sAct, 4096, b_proj, 256, 4096, 512, 1);
}